// Round 4
// baseline (123.366 us; speedup 1.0000x reference)
//
#include <hip/hip_runtime.h>
#include <math.h>

#define NB 4
#define NT 1024
#define NPIX 1296
#define NBINS 512
#define LOOKUP 101
#define PADW 50
#define ODIM 128
#define TT 4                 // t-values per sims block
#define WROWS (TT + 2 * PADW) // 108 window rows per block

typedef _Float16 v2h __attribute__((ext_vector_type(2)));
typedef int v4i __attribute__((ext_vector_type(4)));

__device__ inline float dot2(unsigned a, unsigned b, float acc) {
    union U { unsigned u; v2h h; } ua, ub;
    ua.u = a; ub.u = b;
#if __has_builtin(__builtin_amdgcn_fdot2)
    return __builtin_amdgcn_fdot2(ua.h, ub.h, acc, false);
#else
    return acc + (float)ua.h.x * (float)ub.h.x + (float)ua.h.y * (float)ub.h.y;
#endif
}

// ---------------- Kernel A: per-frame 512-bin histogram -> L2-normalized f16 row
__global__ __launch_bounds__(256) void hist_kernel(const int* __restrict__ frames,
                                                   unsigned short* __restrict__ X) {
    const int frame = blockIdx.x;
    const int tid = threadIdx.x;
    __shared__ unsigned int hist[NBINS];
    for (int i = tid; i < NBINS; i += 256) hist[i] = 0u;
    __syncthreads();

    const v4i* f4 = (const v4i*)(frames + (size_t)frame * NPIX * 3);
    for (int g = tid; g < NPIX / 4; g += 256) {   // 324 groups of 4 px
        v4i a = __builtin_nontemporal_load(&f4[g * 3 + 0]);
        v4i b = __builtin_nontemporal_load(&f4[g * 3 + 1]);
        v4i c = __builtin_nontemporal_load(&f4[g * 3 + 2]);
        int v[12] = {a.x, a.y, a.z, a.w, b.x, b.y, b.z, b.w, c.x, c.y, c.z, c.w};
#pragma unroll
        for (int p = 0; p < 4; ++p) {
            int bin = ((v[3 * p] >> 5) << 6) | ((v[3 * p + 1] >> 5) << 3) | (v[3 * p + 2] >> 5);
            atomicAdd(&hist[bin], 1u);
        }
    }
    __syncthreads();

    float local = 0.f;
    for (int i = tid; i < NBINS; i += 256) {
        float h = (float)hist[i];
        local += h * h;
    }
    for (int off = 32; off >= 1; off >>= 1) local += __shfl_xor(local, off, 64);
    __shared__ float wsum[4];
    if ((tid & 63) == 0) wsum[tid >> 6] = local;
    __syncthreads();
    float inv = 1.0f / fmaxf(sqrtf(wsum[0] + wsum[1] + wsum[2] + wsum[3]), 1e-12f);

    unsigned* xrow = (unsigned*)(X + (size_t)frame * NBINS);
    union U { _Float16 h[2]; unsigned u; } pk;
    pk.h[0] = (_Float16)((float)hist[2 * tid] * inv);
    pk.h[1] = (_Float16)((float)hist[2 * tid + 1] * inv);
    xrow[tid] = pk.u;
}

// ---------------- Kernel B (fused): banded sims + FC + ReLU, TT=4 t per block
// 256 threads = 16 groups of 16 lanes. t-row K-slices live in registers;
// each window-row A-slice is loaded once from L2 and feeds 4 dots.
__global__ __launch_bounds__(256, 4) void simsfc_kernel(const unsigned short* __restrict__ X,
                                                        const float* __restrict__ w,
                                                        const float* __restrict__ bias,
                                                        float* __restrict__ out) {
    const int bid = blockIdx.x;
    // XCD swizzle: each XCD owns a contiguous 512-frame slice of X (L2-resident)
    const int tile = ((bid & 7) << 7) | (bid >> 3);   // 0..1023
    const int b = tile >> 8;                           // 256 tiles per batch
    const int t0 = (tile & 255) * TT;
    const int tid = threadIdx.x;
    const int gid = tid >> 4;        // 0..15 lane-group
    const int kl = tid & 15;         // K-slice lane within group

    __shared__ __align__(16) uint4 st[TT][64];   // 4 t-rows, f16, 4 KB
    __shared__ float win_s[TT][LOOKUP + 3];

    const uint4* Xb4 = (const uint4*)(X + (size_t)b * NT * NBINS);

    // stage the 4 t-rows (coalesced: 256 consecutive uint4)
    {
        int dt = tid >> 6, col = tid & 63;
        st[dt][col] = Xb4[(size_t)(t0 + dt) * 64 + col];
    }
    for (int i = tid; i < TT * (LOOKUP + 3); i += 256) ((float*)win_s)[i] = 0.f;
    __syncthreads();

    // per-lane register cache of the 4 t-row K-slices (16 uint4)
    uint4 tA[TT][4];
#pragma unroll
    for (int dt = 0; dt < TT; ++dt)
#pragma unroll
        for (int i = 0; i < 4; ++i) tA[dt][i] = st[dt][kl + 16 * i];

    for (int it = 0; it < 7; ++it) {
        const int joff = it * 16 + gid;            // 0..111, window-row index
        if (joff >= WROWS) continue;
        const int j = t0 - PADW + joff;
        if (j < 0 || j >= NT) continue;            // win stays zero
        uint4 A[4];
        const uint4* xj = Xb4 + (size_t)j * 64;
#pragma unroll
        for (int i = 0; i < 4; ++i) A[i] = xj[kl + 16 * i];
#pragma unroll
        for (int dt = 0; dt < TT; ++dt) {
            float s = 0.f;
#pragma unroll
            for (int i = 0; i < 4; ++i) {
                s = dot2(A[i].x, tA[dt][i].x, s);
                s = dot2(A[i].y, tA[dt][i].y, s);
                s = dot2(A[i].z, tA[dt][i].z, s);
                s = dot2(A[i].w, tA[dt][i].w, s);
            }
            s += __shfl_xor(s, 1, 64);
            s += __shfl_xor(s, 2, 64);
            s += __shfl_xor(s, 4, 64);
            s += __shfl_xor(s, 8, 64);
            const int l = joff - dt;
            if (kl == 0 && (unsigned)l <= 100u) win_s[dt][l] = s;
        }
    }
    __syncthreads();

    // FC + ReLU: thread -> channel ch, t-rows {g2, g2+2}; one w load feeds 2 rows
    const int ch = tid & 127;
    const int g2 = tid >> 7;
    float acc0 = bias[ch], acc1 = acc0;
#pragma unroll 4
    for (int l = 0; l < LOOKUP; ++l) {
        float wv = w[l * ODIM + ch];
        acc0 = fmaf(win_s[g2][l], wv, acc0);
        acc1 = fmaf(win_s[g2 + 2][l], wv, acc1);
    }
    float* o0 = out + ((size_t)(b * NT + t0 + g2) * ODIM) + ch;
    o0[0] = fmaxf(acc0, 0.f);
    o0[2 * ODIM] = fmaxf(acc1, 0.f);
}

extern "C" void kernel_launch(void* const* d_in, const int* in_sizes, int n_in,
                              void* d_out, int out_size, void* d_ws, size_t ws_size,
                              hipStream_t stream) {
    const int*   frames = (const int*)d_in[0];
    const float* fc_w   = (const float*)d_in[1];
    const float* fc_b   = (const float*)d_in[2];
    float* out = (float*)d_out;

    unsigned short* X = (unsigned short*)d_ws;   // 4096*512 f16 = 4 MB

    hist_kernel  <<<NB * NT, 256, 0, stream>>>(frames, X);
    simsfc_kernel<<<NB * NT / TT, 256, 0, stream>>>(X, fc_w, fc_b, out);
}

// Round 5
// 114.096 us; speedup vs baseline: 1.0812x; 1.0812x over previous
//
#include <hip/hip_runtime.h>
#include <math.h>

#define NB 4
#define NT 1024
#define NPIX 1296
#define NBINS 512
#define LOOKUP 101
#define PADW 50
#define ODIM 128
#define TT 4                 // t-values per sims block
#define WROWS (TT + 2 * PADW) // 108 window rows per block

typedef _Float16 v2h __attribute__((ext_vector_type(2)));

__device__ inline float dot2(unsigned a, unsigned b, float acc) {
    union U { unsigned u; v2h h; } ua, ub;
    ua.u = a; ub.u = b;
#if __has_builtin(__builtin_amdgcn_fdot2)
    return __builtin_amdgcn_fdot2(ua.h, ub.h, acc, false);
#else
    return acc + (float)ua.h.x * (float)ub.h.x + (float)ua.h.y * (float)ub.h.y;
#endif
}

// ---------------- Kernel A: per-frame 512-bin histogram -> L2-normalized f16 row
// Frame staged to LDS with stride-1 int4 loads (coalesced), bins computed from LDS.
__global__ __launch_bounds__(256) void hist_kernel(const int* __restrict__ frames,
                                                   unsigned short* __restrict__ X) {
    const int frame = blockIdx.x;
    const int tid = threadIdx.x;
    __shared__ int raw[NPIX * 3];          // 15552 B
    __shared__ unsigned int hist[NBINS];

    for (int i = tid; i < NBINS; i += 256) hist[i] = 0u;

    const int4* f4 = (const int4*)(frames + (size_t)frame * NPIX * 3);
    int4* r4 = (int4*)raw;
#pragma unroll
    for (int k = 0; k < 4; ++k) {          // 972 int4 total
        int i = tid + k * 256;
        if (i < NPIX * 3 / 4) r4[i] = f4[i];
    }
    __syncthreads();

#pragma unroll
    for (int k = 0; k < 6; ++k) {          // 1296 pixels
        int p = tid + k * 256;
        if (p < NPIX) {
            int r = raw[3 * p], g = raw[3 * p + 1], b = raw[3 * p + 2];
            int bin = ((r >> 5) << 6) | ((g >> 5) << 3) | (b >> 5);
            atomicAdd(&hist[bin], 1u);
        }
    }
    __syncthreads();

    float local = 0.f;
    for (int i = tid; i < NBINS; i += 256) {
        float h = (float)hist[i];
        local += h * h;
    }
    for (int off = 32; off >= 1; off >>= 1) local += __shfl_xor(local, off, 64);
    __shared__ float wsum[4];
    if ((tid & 63) == 0) wsum[tid >> 6] = local;
    __syncthreads();
    float inv = 1.0f / fmaxf(sqrtf(wsum[0] + wsum[1] + wsum[2] + wsum[3]), 1e-12f);

    unsigned* xrow = (unsigned*)(X + (size_t)frame * NBINS);
    union U { _Float16 h[2]; unsigned u; } pk;
    pk.h[0] = (_Float16)((float)hist[2 * tid] * inv);
    pk.h[1] = (_Float16)((float)hist[2 * tid + 1] * inv);
    xrow[tid] = pk.u;
}

// ---------------- Kernel B (fused): banded sims + FC + ReLU, TT=4 t per block
// 256 threads = 16 groups of 16 lanes. t-row K-slices live in registers;
// each window-row A-slice is loaded once from L2 and feeds 4 dots.
__global__ __launch_bounds__(256) void simsfc_kernel(const unsigned short* __restrict__ X,
                                                     const float* __restrict__ w,
                                                     const float* __restrict__ bias,
                                                     float* __restrict__ out) {
    const int bid = blockIdx.x;
    // XCD swizzle: each XCD owns a contiguous 512-frame slice of X (L2-resident)
    const int tile = ((bid & 7) << 7) | (bid >> 3);   // 0..1023
    const int b = tile >> 8;                           // 256 tiles per batch
    const int t0 = (tile & 255) * TT;
    const int tid = threadIdx.x;
    const int gid = tid >> 4;        // 0..15 lane-group
    const int kl = tid & 15;         // K-slice lane within group

    __shared__ __align__(16) uint4 st[TT][64];   // 4 t-rows, f16, 4 KB
    __shared__ float win_s[TT][LOOKUP + 3];

    const uint4* Xb4 = (const uint4*)(X + (size_t)b * NT * NBINS);

    // stage the 4 t-rows (coalesced: 256 consecutive uint4)
    {
        int dt = tid >> 6, col = tid & 63;
        st[dt][col] = Xb4[(size_t)(t0 + dt) * 64 + col];
    }
    for (int i = tid; i < TT * (LOOKUP + 3); i += 256) ((float*)win_s)[i] = 0.f;
    __syncthreads();

    // per-lane register cache of the 4 t-row K-slices (16 uint4)
    uint4 tA[TT][4];
#pragma unroll
    for (int dt = 0; dt < TT; ++dt)
#pragma unroll
        for (int i = 0; i < 4; ++i) tA[dt][i] = st[dt][kl + 16 * i];

    for (int it = 0; it < 7; ++it) {
        const int joff = it * 16 + gid;            // 0..111, window-row index
        if (joff >= WROWS) continue;
        const int j = t0 - PADW + joff;
        if (j < 0 || j >= NT) continue;            // win stays zero
        uint4 A[4];
        const uint4* xj = Xb4 + (size_t)j * 64;
#pragma unroll
        for (int i = 0; i < 4; ++i) A[i] = xj[kl + 16 * i];
#pragma unroll
        for (int dt = 0; dt < TT; ++dt) {
            float s = 0.f;
#pragma unroll
            for (int i = 0; i < 4; ++i) {
                s = dot2(A[i].x, tA[dt][i].x, s);
                s = dot2(A[i].y, tA[dt][i].y, s);
                s = dot2(A[i].z, tA[dt][i].z, s);
                s = dot2(A[i].w, tA[dt][i].w, s);
            }
            s += __shfl_xor(s, 1, 64);
            s += __shfl_xor(s, 2, 64);
            s += __shfl_xor(s, 4, 64);
            s += __shfl_xor(s, 8, 64);
            const int l = joff - dt;
            if (kl == 0 && (unsigned)l <= 100u) win_s[dt][l] = s;
        }
    }
    __syncthreads();

    // FC + ReLU: thread -> channel ch, t-rows {g2, g2+2}; one w load feeds 2 rows
    const int ch = tid & 127;
    const int g2 = tid >> 7;
    float acc0 = bias[ch], acc1 = acc0;
#pragma unroll 4
    for (int l = 0; l < LOOKUP; ++l) {
        float wv = w[l * ODIM + ch];
        acc0 = fmaf(win_s[g2][l], wv, acc0);
        acc1 = fmaf(win_s[g2 + 2][l], wv, acc1);
    }
    float* o0 = out + ((size_t)(b * NT + t0 + g2) * ODIM) + ch;
    o0[0] = fmaxf(acc0, 0.f);
    o0[2 * ODIM] = fmaxf(acc1, 0.f);
}

extern "C" void kernel_launch(void* const* d_in, const int* in_sizes, int n_in,
                              void* d_out, int out_size, void* d_ws, size_t ws_size,
                              hipStream_t stream) {
    const int*   frames = (const int*)d_in[0];
    const float* fc_w   = (const float*)d_in[1];
    const float* fc_b   = (const float*)d_in[2];
    float* out = (float*)d_out;

    unsigned short* X = (unsigned short*)d_ws;   // 4096*512 f16 = 4 MB

    hist_kernel  <<<NB * NT, 256, 0, stream>>>(frames, X);
    simsfc_kernel<<<NB * NT / TT, 256, 0, stream>>>(X, fc_w, fc_b, out);
}